// Round 9
// baseline (1671.477 us; speedup 1.0000x reference)
//
#include <hip/hip_runtime.h>
#include <hip/hip_cooperative_groups.h>

namespace cg = cooperative_groups;

// LSTM S=512,B=128,IN=256,H=512 — persistent kernel, 256 blocks =
// 8 rowgroups(16 batch rows) x 32 colgroups(16 hidden cols; 4 gate-waves).
// Round 9: flag-release protocol, ALWAYS-LLC (no L2 mode — rounds 5-7 showed
// the L2 id-handshake is unsound across graph replays).
//   producer: bf16 payload store (sc0sc1) -> wave-local vmcnt(0) ->
//             lane0 per-WAVE flag store (monotone counter, no barrier)
//   consumer: poll 128 flag dwords (512B/round) -> ONE 16KB payload read
// Own-block wave flags double as the LDS reuse guard (poll t+1 implies all
// own waves finished step-t MFMA reads) -> still 2 barriers/step.

#define SQ   512
#define BB   128
#define IN_  256
#define HH   512
#define RG   8
#define CGN  32
#define FLAGS_DW   1024            // 4 KB head: flags[r*128 + cg*4 + wave]
#define RINGHALF_H (BB * HH)       // bf16 elements per ring half

typedef float    f32x4 __attribute__((ext_vector_type(4)));
typedef short    s16x8 __attribute__((ext_vector_type(8)));
typedef unsigned u32x2 __attribute__((ext_vector_type(2)));
typedef unsigned u32x4 __attribute__((ext_vector_type(4)));

struct P {
  const float *x, *h0, *c0;
  const float *W[4], *bW[4], *U[4], *bU[4];   // gate order f,i,o,g
  float* out;              // [SQ][BB][HH] h_seq, then [BB][HH] h, [BB][HH] c
  unsigned* flags;         // [RG][CGN][4] monotone step counters
  unsigned short* ring;    // [2][BB][HH] bf16 h payload
  int mode;                // 0 = flag protocol, 2 = gridsync fallback
};

__device__ __forceinline__ unsigned f2b(float f) {
  unsigned u = __float_as_uint(f);
  return (u + 0x7FFFu + ((u >> 16) & 1u)) >> 16;   // RNE f32->bf16
}
__device__ __forceinline__ float sigm(float x) { return 1.f / (1.f + __expf(-x)); }
__device__ __forceinline__ float tanh_(float x) {
  float e = __expf(-2.f * fabsf(x));
  float t = (1.f - e) / (1.f + e);
  return copysignf(t, x);
}
__device__ __forceinline__ u32x4 pack8(f32x4 a, f32x4 b) {
  u32x4 d;
  d.x = f2b(a.x) | (f2b(a.y) << 16);
  d.y = f2b(a.z) | (f2b(a.w) << 16);
  d.z = f2b(b.x) | (f2b(b.y) << 16);
  d.w = f2b(b.z) | (f2b(b.w) << 16);
  return d;
}

// 4x dwordx4 contiguous 64B, ONE waitcnt, LLC-coherent.
#define LOAD4_LLC(c0_,c1_,c2_,c3_,ptr_)                                      \
  asm volatile(                                                              \
    "global_load_dwordx4 %0, %4, off sc0 sc1\n\t"                            \
    "global_load_dwordx4 %1, %4, off offset:16 sc0 sc1\n\t"                  \
    "global_load_dwordx4 %2, %4, off offset:32 sc0 sc1\n\t"                  \
    "global_load_dwordx4 %3, %4, off offset:48 sc0 sc1\n\t"                  \
    "s_waitcnt vmcnt(0)"                                                     \
    : "=&v"(c0_), "=&v"(c1_), "=&v"(c2_), "=&v"(c3_)                         \
    : "v"(ptr_) : "memory")

// 8x dwordx4 from base+{0,256,...,1792}B (gridsync fallback h read)
#define LOAD8_LLC(c0_,c1_,c2_,c3_,c4_,c5_,c6_,c7_,ptr_)                      \
  asm volatile(                                                              \
    "global_load_dwordx4 %0, %8, off sc0 sc1\n\t"                            \
    "global_load_dwordx4 %1, %8, off offset:256 sc0 sc1\n\t"                 \
    "global_load_dwordx4 %2, %8, off offset:512 sc0 sc1\n\t"                 \
    "global_load_dwordx4 %3, %8, off offset:768 sc0 sc1\n\t"                 \
    "global_load_dwordx4 %4, %8, off offset:1024 sc0 sc1\n\t"                \
    "global_load_dwordx4 %5, %8, off offset:1280 sc0 sc1\n\t"                \
    "global_load_dwordx4 %6, %8, off offset:1536 sc0 sc1\n\t"                \
    "global_load_dwordx4 %7, %8, off offset:1792 sc0 sc1\n\t"                \
    "s_waitcnt vmcnt(0)"                                                     \
    : "=&v"(c0_), "=&v"(c1_), "=&v"(c2_), "=&v"(c3_),                        \
      "=&v"(c4_), "=&v"(c5_), "=&v"(c6_), "=&v"(c7_)                         \
    : "v"(ptr_) : "memory")

__global__ void __launch_bounds__(256, 1) lstm_all(P p) {
  __shared__ unsigned short Hs[16][512];      // h bf16, rows 1024B, XOR swz
  __shared__ unsigned short Xs[2][16][256];   // x bf16 double-buf, rows 512B
  __shared__ float gbuf[4][16][17];

  const int tid = threadIdx.x;
  const int bid = blockIdx.x;
  const int r   = bid & 7;          // rowgroup
  const int cgi = bid >> 3;         // colgroup
  const int rb  = r * 16;
  const int hcb = cgi * 16;

  const int w   = tid >> 6;         // wave = gate (0=f,1=i,2=o,3=g)
  const int l   = tid & 63;
  const int l16 = l & 15;
  const int lk  = l >> 4;
  const int row16 = tid >> 4;       // staging/update row 0..15
  const int n16   = tid & 15;

  // ---- per-wave B fragments (W|U) -> registers, bf16, once ----
  const int col = hcb + l16;
  s16x8 bfrag[24];
#pragma unroll
  for (int kk = 0; kk < 24; ++kk) {
    int k = kk * 32 + lk * 8;
    const float* src = (kk < 8) ? (p.W[w] + (size_t)col * IN_ + k)
                                : (p.U[w] + (size_t)col * HH + (k - IN_));
    f32x4 a = *(const f32x4*)src;
    f32x4 b = *(const f32x4*)(src + 4);
    s16x8 v;
    v[0]=(short)f2b(a.x); v[1]=(short)f2b(a.y); v[2]=(short)f2b(a.z); v[3]=(short)f2b(a.w);
    v[4]=(short)f2b(b.x); v[5]=(short)f2b(b.y); v[6]=(short)f2b(b.z); v[7]=(short)f2b(b.w);
    bfrag[kk] = v;
  }
  const float bias = p.bW[w][col] + p.bU[w][col];
  float cval = p.c0[(size_t)(rb + row16) * HH + hcb + n16];

  const int wswz = (row16 & 7) << 4;   // staging-row byte-XOR key
  const int rswz = (l16 & 7) << 4;     // mfma-read byte-XOR key
  char* HsB = (char*)&Hs[0][0];
  char* XsB = (char*)&Xs[0][0][0];

  const unsigned* fpoll = (p.mode == 0) ? (p.flags + r * 128 + l * 2) : nullptr;
  unsigned* fpub = (p.mode == 0) ? (p.flags + r * 128 + cgi * 4 + w) : nullptr;

  // ---- prologue: x(t=0) into registers ----
  f32x4 xg0, xg1, xg2, xg3;
  {
    const float* xs = p.x + (size_t)(rb + row16) * IN_ + n16 * 16;
    xg0 = *(const f32x4*)(xs);
    xg1 = *(const f32x4*)(xs + 4);
    xg2 = *(const f32x4*)(xs + 8);
    xg3 = *(const f32x4*)(xs + 12);
  }

  for (int t = 0; t < SQ; ++t) {
    // ---- A) Xs[t&1] <- xreg; issue x(t+1) loads (hide under the poll) ----
    {
      char* xrow = XsB + (t & 1) * 8192 + row16 * 512;
      *(u32x4*)(xrow + ((n16 * 32)      ^ wswz)) = pack8(xg0, xg1);
      *(u32x4*)(xrow + ((n16 * 32 + 16) ^ wswz)) = pack8(xg2, xg3);
      if (t + 1 < SQ) {
        const float* xs = p.x + ((size_t)(t + 1) * BB + rb + row16) * IN_ + n16 * 16;
        xg0 = *(const f32x4*)(xs);
        xg1 = *(const f32x4*)(xs + 4);
        xg2 = *(const f32x4*)(xs + 8);
        xg3 = *(const f32x4*)(xs + 12);
      }
    }

    // ---- B) obtain h_{t-1} into Hs (bf16, swizzled) ----
    char* hrow = HsB + row16 * 1024;
    if (t == 0) {
      const float* hs = p.h0 + (size_t)(rb + row16) * HH + n16 * 32;
#pragma unroll
      for (int q = 0; q < 4; ++q) {
        f32x4 a = *(const f32x4*)(hs + q * 8);
        f32x4 b = *(const f32x4*)(hs + q * 8 + 4);
        *(u32x4*)(hrow + ((n16 * 64 + q * 16) ^ wswz)) = pack8(a, b);
      }
    } else if (p.mode == 0) {
      // B1) poll 128 per-wave flags (512B/round, all waves independently)
      const unsigned tg = (unsigned)t;
      int spin = 0;
      for (;;) {
        u32x2 fv;
        asm volatile("global_load_dwordx2 %0, %1, off sc0 sc1\n\ts_waitcnt vmcnt(0)"
                     : "=v"(fv) : "v"(fpoll) : "memory");
        if (__all((int)(fv.x >= tg && fv.y >= tg))) break;
        if (++spin > (1 << 13)) break;   // bounded: fail loud, never hang
        if (spin > 8) __builtin_amdgcn_s_sleep(1);
      }
      // B2) ONE 64B payload read per thread (flags guarantee freshness;
      //     producer ordered payload before flag with wave-local vmcnt(0))
      const unsigned short* hb = p.ring + (size_t)((t - 1) & 1) * RINGHALF_H
                               + (size_t)(rb + row16) * HH + n16 * 32;
      u32x4 d0, d1, d2, d3;
      LOAD4_LLC(d0, d1, d2, d3, hb);
      *(u32x4*)(hrow + ((n16 * 64)      ^ wswz)) = d0;
      *(u32x4*)(hrow + ((n16 * 64 + 16) ^ wswz)) = d1;
      *(u32x4*)(hrow + ((n16 * 64 + 32) ^ wswz)) = d2;
      *(u32x4*)(hrow + ((n16 * 64 + 48) ^ wswz)) = d3;
    } else {
      // gridsync fallback: f32 h from d_out via LLC
      cg::this_grid().sync();
      const float* hp = p.out + ((size_t)(t - 1) * BB + rb + row16) * HH + n16 * 32;
      u32x4 a0,a1,a2,a3,a4,a5,a6,a7;
      LOAD8_LLC(a0,a1,a2,a3,a4,a5,a6,a7,hp);
      f32x4 av[8];
      av[0]=__builtin_bit_cast(f32x4,a0); av[1]=__builtin_bit_cast(f32x4,a1);
      av[2]=__builtin_bit_cast(f32x4,a2); av[3]=__builtin_bit_cast(f32x4,a3);
      av[4]=__builtin_bit_cast(f32x4,a4); av[5]=__builtin_bit_cast(f32x4,a5);
      av[6]=__builtin_bit_cast(f32x4,a6); av[7]=__builtin_bit_cast(f32x4,a7);
#pragma unroll
      for (int q = 0; q < 4; ++q)
        *(u32x4*)(hrow + ((n16 * 64 + q * 16) ^ wswz)) = pack8(av[2*q], av[2*q+1]);
    }
    __syncthreads();   // Xs[t&1] + Hs ready

    // ---- D) 24 MFMAs: 8 from Xs (K=0..255), 16 from Hs (K=256..767) ----
    f32x4 acc0 = { bias, bias, bias, bias };
    f32x4 acc1 = { 0.f, 0.f, 0.f, 0.f };
    const char* xr = XsB + (t & 1) * 8192 + l16 * 512;
    const char* hr = HsB + l16 * 1024;
#pragma unroll
    for (int kp = 0; kp < 8; kp += 2) {
      s16x8 a0 = *(const s16x8*)(xr + ((kp * 64 + lk * 16)       ^ rswz));
      s16x8 a1 = *(const s16x8*)(xr + (((kp + 1) * 64 + lk * 16) ^ rswz));
      acc0 = __builtin_amdgcn_mfma_f32_16x16x32_bf16(a0, bfrag[kp],     acc0, 0, 0, 0);
      acc1 = __builtin_amdgcn_mfma_f32_16x16x32_bf16(a1, bfrag[kp + 1], acc1, 0, 0, 0);
    }
#pragma unroll
    for (int kp = 0; kp < 16; kp += 2) {
      s16x8 a0 = *(const s16x8*)(hr + ((kp * 64 + lk * 16)       ^ rswz));
      s16x8 a1 = *(const s16x8*)(hr + (((kp + 1) * 64 + lk * 16) ^ rswz));
      acc0 = __builtin_amdgcn_mfma_f32_16x16x32_bf16(a0, bfrag[8 + kp], acc0, 0, 0, 0);
      acc1 = __builtin_amdgcn_mfma_f32_16x16x32_bf16(a1, bfrag[9 + kp], acc1, 0, 0, 0);
    }

    // ---- E) activations -> gbuf (D-frag: row=lk*4+rr, col=l16) ----
#pragma unroll
    for (int rr = 0; rr < 4; ++rr) {
      float v = acc0[rr] + acc1[rr];
      v = (w < 3) ? sigm(v) : tanh_(v);
      gbuf[w][lk * 4 + rr][l16] = v;
    }
    __syncthreads();

    // ---- F) cell update + publish ----
    float f = gbuf[0][row16][n16];
    float i = gbuf[1][row16][n16];
    float o = gbuf[2][row16][n16];
    float g = gbuf[3][row16][n16];
    cval = f * cval + i * g;
    float h = o * tanh_(cval);

    size_t oidx = ((size_t)t * BB + rb + row16) * HH + hcb + n16;
    if (p.mode == 0) {
      // payload (bf16, sc0sc1) -> wave-local drain -> lane0 wave flag
      unsigned hb16 = f2b(h);
      unsigned short* dst = p.ring + (size_t)(t & 1) * RINGHALF_H
                          + (size_t)(rb + row16) * HH + hcb + n16;
      asm volatile("global_store_short %0, %1, off sc0 sc1"
                   :: "v"(dst), "v"(hb16) : "memory");
      asm volatile("s_waitcnt vmcnt(0)" ::: "memory");
      if ((tid & 63) == 0) {
        unsigned fv2 = (unsigned)(t + 1);
        asm volatile("global_store_dword %0, %1, off sc0 sc1"
                     :: "v"(fpub), "v"(fv2) : "memory");
      }
      __builtin_nontemporal_store(h, p.out + oidx);   // off critical path
    } else {
      asm volatile("global_store_dword %0, %1, off sc0 sc1"
                   :: "v"(p.out + oidx), "v"(h) : "memory");
      asm volatile("s_waitcnt vmcnt(0)" ::: "memory");
    }
    if (t == SQ - 1) {
      size_t base = (size_t)SQ * BB * HH;
      size_t idx2 = (size_t)(rb + row16) * HH + hcb + n16;
      p.out[base + idx2] = h;
      p.out[base + (size_t)BB * HH + idx2] = cval;
    }
    // reuse guards: Hs/Xs overwrite at t+1 gated by the flag poll (own-block
    // wave flags imply step-t MFMA reads done); gbuf by the staging barrier
  }
}

extern "C" void kernel_launch(void* const* d_in, const int* in_sizes, int n_in,
                              void* d_out, int out_size, void* d_ws, size_t ws_size,
                              hipStream_t stream) {
  P p;
  p.x  = (const float*)d_in[0];
  p.h0 = (const float*)d_in[1];
  p.c0 = (const float*)d_in[2];
  for (int g = 0; g < 4; ++g) {
    p.W[g]  = (const float*)d_in[3 + 4 * g];
    p.bW[g] = (const float*)d_in[4 + 4 * g];
    p.U[g]  = (const float*)d_in[5 + 4 * g];
    p.bU[g] = (const float*)d_in[6 + 4 * g];
  }
  p.out = (float*)d_out;

  const size_t need = FLAGS_DW * 4 + (size_t)2 * RINGHALF_H * 2;   // ~260 KB
  const bool ws_ok = (d_ws != nullptr) && (ws_size >= need);
  p.mode  = ws_ok ? 0 : 2;
  p.flags = ws_ok ? (unsigned*)d_ws : nullptr;
  p.ring  = ws_ok ? (unsigned short*)((unsigned*)d_ws + FLAGS_DW) : nullptr;
  if (ws_ok) hipMemsetAsync(d_ws, 0, FLAGS_DW * 4, stream);  // flags = 0

  void* args[] = { &p };
  hipError_t e = hipLaunchCooperativeKernel((const void*)lstm_all,
                                            dim3(RG * CGN), dim3(256),
                                            args, 0, stream);
  if (e != hipSuccess) {
    // plain launch: 256 blocks at 1/CU are co-resident; protocol still valid
    hipLaunchKernelGGL(lstm_all, dim3(RG * CGN), dim3(256), 0, stream, p);
  }
}